// Round 3
// baseline (360.720 us; speedup 1.0000x reference)
//
#include <hip/hip_runtime.h>
#include <hip/hip_bf16.h>

typedef __bf16 bf16x8 __attribute__((ext_vector_type(8)));
typedef float floatx4 __attribute__((ext_vector_type(4)));

#define MFMA16(a, b, c) __builtin_amdgcn_mfma_f32_16x16x32_bf16((a), (b), (c), 0, 0, 0)

static constexpr int Bb = 8, Nn = 2048, Mm = 2048, Dd = 256;

// Load 8 consecutive fp32 and round-to-nearest bf16.
__device__ inline bf16x8 cvt8(const float* __restrict__ p)
{
    float4 f0 = *reinterpret_cast<const float4*>(p);
    float4 f1 = *reinterpret_cast<const float4*>(p + 4);
    bf16x8 r;
    r[0] = (__bf16)f0.x; r[1] = (__bf16)f0.y; r[2] = (__bf16)f0.z; r[3] = (__bf16)f0.w;
    r[4] = (__bf16)f1.x; r[5] = (__bf16)f1.y; r[6] = (__bf16)f1.z; r[7] = (__bf16)f1.w;
    return r;
}

// hi/lo split: x = hi + lo with hi = bf16(x), lo = bf16(x - hi). ~16-bit extra mantissa.
__device__ inline void cvt8_split(const float* __restrict__ p, bf16x8& h, bf16x8& l)
{
    float4 f0 = *reinterpret_cast<const float4*>(p);
    float4 f1 = *reinterpret_cast<const float4*>(p + 4);
    float f[8] = {f0.x, f0.y, f0.z, f0.w, f1.x, f1.y, f1.z, f1.w};
#pragma unroll
    for (int i = 0; i < 8; ++i) {
        __bf16 hb = (__bf16)f[i];
        h[i] = hb;
        l[i] = (__bf16)(f[i] - (float)hb);
    }
}

// ---------------------------------------------------------------------------
// Kernel 1: q = x @ W^T + b, fp32-accurate via 3-term bf16 split MFMA.
// 256 blocks x 256 thr; wave w computes rows blk*64 + w*16, all 256 cols.
// ---------------------------------------------------------------------------
__global__ __launch_bounds__(256, 1)
void qproj_kernel(const float* __restrict__ x, const float* __restrict__ W,
                  const float* __restrict__ bias, float* __restrict__ q)
{
    const int lane = threadIdx.x & 63;
    const int wave = threadIdx.x >> 6;
    const int lo = lane & 15, hi = lane >> 4;
    const long r0 = (long)blockIdx.x * 64 + wave * 16;

    floatx4 acc[16];
#pragma unroll
    for (int j = 0; j < 16; ++j) acc[j] = (floatx4)0.0f;

    const float* xrow = x + (r0 + lo) * Dd + hi * 8;
#pragma unroll
    for (int kk = 0; kk < 8; ++kk) {
        bf16x8 ah, al;
        cvt8_split(xrow + kk * 32, ah, al);
#pragma unroll
        for (int j = 0; j < 16; ++j) {
            // B[k=d][n=e]: e = j*16+lo, k = kk*32 + hi*8 + i -> W[e][k] contiguous
            bf16x8 bh, bl;
            cvt8_split(W + (size_t)(j * 16 + lo) * Dd + kk * 32 + hi * 8, bh, bl);
            acc[j] = MFMA16(ah, bh, acc[j]);
            acc[j] = MFMA16(ah, bl, acc[j]);
            acc[j] = MFMA16(al, bh, acc[j]);
        }
    }
    // C layout: col = lo (= e), row = hi*4 + r (= n)
#pragma unroll
    for (int j = 0; j < 16; ++j) {
        float bv = bias[j * 16 + lo];
#pragma unroll
        for (int r = 0; r < 4; ++r) {
            q[(size_t)(r0 + hi * 4 + r) * Dd + j * 16 + lo] = acc[j][r] + bv;
        }
    }
}

// ---------------------------------------------------------------------------
// Kernel 2: FiT[b][d][m] = bf16(Fi[b][m][d])   (fp32 -> bf16 transpose via LDS)
// grid: 8 * 32(mt) * 4(dt) = 1024 blocks, tile 64(m) x 64(d)
// ---------------------------------------------------------------------------
__global__ __launch_bounds__(256, 4)
void transpose_kernel(const float* __restrict__ Fi, __bf16* __restrict__ FiT)
{
    __shared__ __align__(16) unsigned short tile[64][72];  // +8 pad
    const int bid = blockIdx.x;
    const int b  = bid >> 7;
    const int mt = (bid >> 2) & 31;
    const int dt = bid & 3;
    const int t = threadIdx.x;

    {
        const int i = t >> 2, jc = (t & 3) * 16;
        const float* src = Fi + ((size_t)b * Mm + mt * 64 + i) * Dd + dt * 64 + jc;
        union { bf16x8 v; uint4 u; } p0, p1;
        p0.v = cvt8(src);
        p1.v = cvt8(src + 8);
        *(uint4*)&tile[i][jc]     = p0.u;
        *(uint4*)&tile[i][jc + 8] = p1.u;
    }
    __syncthreads();
    {
        const int d = t >> 2, mc = (t & 3) * 16;
        unsigned short* dst = reinterpret_cast<unsigned short*>(FiT)
            + ((size_t)b * Dd + dt * 64 + d) * Mm + mt * 64 + mc;
        union { uint4 v[2]; unsigned short s[16]; } u;
#pragma unroll
        for (int s = 0; s < 16; ++s) u.s[s] = tile[mc + s][d];
        *(uint4*)dst       = u.v[0];
        *(uint4*)(dst + 8) = u.v[1];
    }
}

// ---------------------------------------------------------------------------
// Kernel 3: flash attention, fp32-accurate logits via hi/lo split QK.
// 256 blocks (batch = bid&7 -> XCD-affine), 4 waves x 16 q-rows, KV tile 32.
// ---------------------------------------------------------------------------
__global__ __launch_bounds__(256, 1)
void flash_kernel(const float* __restrict__ q, const float* __restrict__ Fi,
                  const __bf16* __restrict__ FiT, float* __restrict__ out)
{
    __shared__ __align__(16) __bf16 sFiLh[32][264];  // hi plane, [m][d] pad 256->264
    __shared__ __align__(16) __bf16 sFiLl[32][264];  // lo plane
    __shared__ __align__(16) __bf16 sFiT[256][40];   // [d][m], pad 32->40
    __shared__ __align__(16) __bf16 sP[4][16][40];   // per-wave P, [n][m]

    const int bid = blockIdx.x;
    const int b  = bid & 7;
    const int nt = bid >> 3;
    const int tid = threadIdx.x;
    const int lane = tid & 63, wave = tid >> 6;
    const int lo = lane & 15, hi = lane >> 4;
    const long n0 = (long)nt * 64 + wave * 16;

    // Q fragments hi/lo, A layout: A[m=lo][k = kk*32 + hi*8 + j]
    bf16x8 qh[8], ql[8];
    const float* qbase = q + ((size_t)b * Nn + n0 + lo) * Dd + hi * 8;
#pragma unroll
    for (int kk = 0; kk < 8; ++kk) cvt8_split(qbase + kk * 32, qh[kk], ql[kk]);

    floatx4 o[16];
#pragma unroll
    for (int t = 0; t < 16; ++t) o[t] = (floatx4)0.0f;
    float m_i[4] = {-INFINITY, -INFINITY, -INFINITY, -INFINITY};
    float l_i[4] = {0.f, 0.f, 0.f, 0.f};

    // staging assignments
    const int sm = tid >> 3;            // 0..31 : sFiL row
    const int sd = (tid & 7) * 32;      // col group of 32 elements
    const float* gL = Fi + ((size_t)b * Mm + sm) * Dd + sd;
    const unsigned short* gT = reinterpret_cast<const unsigned short*>(FiT)
        + ((size_t)b * Dd + tid) * Mm;

    for (int mt = 0; mt < Mm / 32; ++mt) {
        const int m0 = mt * 32;
        // ---- stage Fi tile (fp32 -> hi/lo bf16) and FiT tile (bf16 copy)
        {
            const float* s = gL + (size_t)m0 * Dd;
#pragma unroll
            for (int i = 0; i < 4; ++i) {
                bf16x8 h, l;
                cvt8_split(s + i * 8, h, l);
                *(bf16x8*)&sFiLh[sm][sd + i * 8] = h;
                *(bf16x8*)&sFiLl[sm][sd + i * 8] = l;
            }
            const unsigned short* s2 = gT + m0;
#pragma unroll
            for (int i = 0; i < 4; ++i)
                *(uint4*)&sFiT[tid][i * 8] = *(const uint4*)(s2 + i * 8);
        }
        __syncthreads();

        // ---- S = q . Fi^T, fp32-accurate: qh*kh + qh*kl + ql*kh
        floatx4 s0 = (floatx4)0.0f, s1 = (floatx4)0.0f;
#pragma unroll
        for (int kk = 0; kk < 8; ++kk) {
            bf16x8 b0h = *reinterpret_cast<const bf16x8*>(&sFiLh[lo][kk * 32 + hi * 8]);
            bf16x8 b0l = *reinterpret_cast<const bf16x8*>(&sFiLl[lo][kk * 32 + hi * 8]);
            bf16x8 b1h = *reinterpret_cast<const bf16x8*>(&sFiLh[16 + lo][kk * 32 + hi * 8]);
            bf16x8 b1l = *reinterpret_cast<const bf16x8*>(&sFiLl[16 + lo][kk * 32 + hi * 8]);
            s0 = MFMA16(qh[kk], b0h, s0);
            s0 = MFMA16(qh[kk], b0l, s0);
            s0 = MFMA16(ql[kk], b0h, s0);
            s1 = MFMA16(qh[kk], b1h, s1);
            s1 = MFMA16(qh[kk], b1l, s1);
            s1 = MFMA16(ql[kk], b1h, s1);
        }

        // ---- online softmax (C layout: col=lo, row=hi*4+r; reduce across 16 lanes)
        float alpha[4];
#pragma unroll
        for (int r = 0; r < 4; ++r) {
            float mc = fmaxf(s0[r], s1[r]);
            mc = fmaxf(mc, __shfl_xor(mc, 1));
            mc = fmaxf(mc, __shfl_xor(mc, 2));
            mc = fmaxf(mc, __shfl_xor(mc, 4));
            mc = fmaxf(mc, __shfl_xor(mc, 8));
            const float mnew = fmaxf(m_i[r], mc);
            alpha[r] = __expf(m_i[r] - mnew);
            // round p to bf16 FIRST; accumulate l over the ROUNDED values so the
            // PV numerator and the l denominator use identical weights.
            const __bf16 p0b = (__bf16)__expf(s0[r] - mnew);
            const __bf16 p1b = (__bf16)__expf(s1[r] - mnew);
            float ps = (float)p0b + (float)p1b;
            ps += __shfl_xor(ps, 1);
            ps += __shfl_xor(ps, 2);
            ps += __shfl_xor(ps, 4);
            ps += __shfl_xor(ps, 8);
            l_i[r] = l_i[r] * alpha[r] + ps;
            m_i[r] = mnew;
            sP[wave][hi * 4 + r][lo]      = p0b;
            sP[wave][hi * 4 + r][16 + lo] = p1b;
        }
#pragma unroll
        for (int t = 0; t < 16; ++t) {
            floatx4 ot = o[t];
#pragma unroll
            for (int r = 0; r < 4; ++r) ot[r] *= alpha[r];
            o[t] = ot;
        }

        // ---- O += P @ Fi  (A from sP, B from sFiT; K = 32)
        bf16x8 pa = *reinterpret_cast<const bf16x8*>(&sP[wave][lo][hi * 8]);
#pragma unroll
        for (int t = 0; t < 16; ++t) {
            bf16x8 bv = *reinterpret_cast<const bf16x8*>(&sFiT[t * 16 + lo][hi * 8]);
            o[t] = MFMA16(pa, bv, o[t]);
        }
        __syncthreads();
    }

    // ---- epilogue: O / l, store fp32
#pragma unroll
    for (int r = 0; r < 4; ++r) {
        const float inv = 1.0f / l_i[r];
        const size_t row = (size_t)b * Nn + n0 + hi * 4 + r;
#pragma unroll
        for (int t = 0; t < 16; ++t)
            out[row * Dd + t * 16 + lo] = o[t][r] * inv;
    }
}

// ---------------------------------------------------------------------------
extern "C" void kernel_launch(void* const* d_in, const int* in_sizes, int n_in,
                              void* d_out, int out_size, void* d_ws, size_t ws_size,
                              hipStream_t stream)
{
    const float* x    = (const float*)d_in[0];
    const float* Fi   = (const float*)d_in[1];
    const float* W    = (const float*)d_in[2];
    const float* bias = (const float*)d_in[3];
    float* out = (float*)d_out;

    float*  q_ws = (float*)d_ws;                                    // 16.8 MB fp32
    __bf16* FiT  = (__bf16*)(q_ws + (size_t)Bb * Nn * Dd);          // 8.4 MB bf16

    hipLaunchKernelGGL(qproj_kernel, dim3(256), dim3(256), 0, stream, x, W, bias, q_ws);
    hipLaunchKernelGGL(transpose_kernel, dim3(1024), dim3(256), 0, stream, Fi, FiT);
    hipLaunchKernelGGL(flash_kernel, dim3(256), dim3(256), 0, stream, q_ws, Fi, FiT, out);
}

// Round 4
// 296.357 us; speedup vs baseline: 1.2172x; 1.2172x over previous
//
#include <hip/hip_runtime.h>
#include <hip/hip_bf16.h>

typedef _Float16 half8 __attribute__((ext_vector_type(8)));
typedef float floatx4 __attribute__((ext_vector_type(4)));

#define MFMA16H(a, b, c) __builtin_amdgcn_mfma_f32_16x16x32_f16((a), (b), (c), 0, 0, 0)

static constexpr int Bb = 8, Nn = 2048, Mm = 2048, Dd = 256;

// Load 8 consecutive fp32, round to fp16.
__device__ inline half8 cvt8h(const float* __restrict__ p)
{
    float4 f0 = *reinterpret_cast<const float4*>(p);
    float4 f1 = *reinterpret_cast<const float4*>(p + 4);
    half8 r;
    r[0] = (_Float16)f0.x; r[1] = (_Float16)f0.y; r[2] = (_Float16)f0.z; r[3] = (_Float16)f0.w;
    r[4] = (_Float16)f1.x; r[5] = (_Float16)f1.y; r[6] = (_Float16)f1.z; r[7] = (_Float16)f1.w;
    return r;
}

// hi/lo fp16 split: x = hi + lo, residual ~2^-22 rel.
__device__ inline void cvt8h_split(const float* __restrict__ p, half8& h, half8& l)
{
    float4 f0 = *reinterpret_cast<const float4*>(p);
    float4 f1 = *reinterpret_cast<const float4*>(p + 4);
    float f[8] = {f0.x, f0.y, f0.z, f0.w, f1.x, f1.y, f1.z, f1.w};
#pragma unroll
    for (int i = 0; i < 8; ++i) {
        _Float16 hh = (_Float16)f[i];
        h[i] = hh;
        l[i] = (_Float16)(f[i] - (float)hh);
    }
}

// ---------------------------------------------------------------------------
// Kernel 1: q = fp16( x @ W^T + b ), fp32-grade GEMM via 3-term fp16 split.
// 256 blocks x 256 thr; wave w computes rows blk*64 + w*16, all 256 cols.
// ---------------------------------------------------------------------------
__global__ __launch_bounds__(256, 1)
void qproj_kernel(const float* __restrict__ x, const float* __restrict__ W,
                  const float* __restrict__ bias, _Float16* __restrict__ q)
{
    const int lane = threadIdx.x & 63;
    const int wave = threadIdx.x >> 6;
    const int lo = lane & 15, hi = lane >> 4;
    const long r0 = (long)blockIdx.x * 64 + wave * 16;

    floatx4 acc[16];
#pragma unroll
    for (int j = 0; j < 16; ++j) acc[j] = (floatx4)0.0f;

    const float* xrow = x + (r0 + lo) * Dd + hi * 8;
#pragma unroll
    for (int kk = 0; kk < 8; ++kk) {
        half8 ah, al;
        cvt8h_split(xrow + kk * 32, ah, al);
#pragma unroll
        for (int j = 0; j < 16; ++j) {
            half8 bh, bl;
            cvt8h_split(W + (size_t)(j * 16 + lo) * Dd + kk * 32 + hi * 8, bh, bl);
            acc[j] = MFMA16H(ah, bh, acc[j]);
            acc[j] = MFMA16H(ah, bl, acc[j]);
            acc[j] = MFMA16H(al, bh, acc[j]);
        }
    }
    // C layout: col = lo (= e), row = hi*4 + r (= n)
#pragma unroll
    for (int j = 0; j < 16; ++j) {
        float bv = bias[j * 16 + lo];
#pragma unroll
        for (int r = 0; r < 4; ++r) {
            q[(size_t)(r0 + hi * 4 + r) * Dd + j * 16 + lo] = (_Float16)(acc[j][r] + bv);
        }
    }
}

// ---------------------------------------------------------------------------
// Kernel 2: FiH[b][m][d] = fp16(Fi) and FiT[b][d][m] = fp16(Fi) transposed.
// grid: 8 * 32(mt) * 4(dt) = 1024 blocks, tile 64(m) x 64(d), 256 thr.
// ---------------------------------------------------------------------------
__global__ __launch_bounds__(256, 4)
void prep_kernel(const float* __restrict__ Fi, _Float16* __restrict__ FiH,
                 _Float16* __restrict__ FiT)
{
    __shared__ __align__(16) unsigned short tile[64][72];  // +8 pad
    const int bid = blockIdx.x;
    const int b  = bid >> 7;
    const int mt = (bid >> 2) & 31;
    const int dt = bid & 3;
    const int t = threadIdx.x;

    {
        const int i = t >> 2, jc = (t & 3) * 16;
        const float* src = Fi + ((size_t)b * Mm + mt * 64 + i) * Dd + dt * 64 + jc;
        union { half8 v; uint4 u; } p0, p1;
        p0.v = cvt8h(src);
        p1.v = cvt8h(src + 8);
        *(uint4*)&tile[i][jc]     = p0.u;
        *(uint4*)&tile[i][jc + 8] = p1.u;
        // straight fp16 copy (coalesced)
        unsigned short* dh = reinterpret_cast<unsigned short*>(FiH)
            + ((size_t)b * Mm + mt * 64 + i) * Dd + dt * 64 + jc;
        *(uint4*)dh       = p0.u;
        *(uint4*)(dh + 8) = p1.u;
    }
    __syncthreads();
    {
        const int d = t >> 2, mc = (t & 3) * 16;
        unsigned short* dst = reinterpret_cast<unsigned short*>(FiT)
            + ((size_t)b * Dd + dt * 64 + d) * Mm + mt * 64 + mc;
        union { uint4 v[2]; unsigned short s[16]; } u;
#pragma unroll
        for (int s = 0; s < 16; ++s) u.s[s] = tile[mc + s][d];
        *(uint4*)dst       = u.v[0];
        *(uint4*)(dst + 8) = u.v[1];
    }
}

// ---------------------------------------------------------------------------
// Kernel 3: flash attention, no K-loop barriers, B-frags direct from L2.
// grid 256 (b = bid&7 -> XCD-affine, nt = bid>>3), 4 waves:
//   wave = (kh<<1)|rg : rg = row-group (32 rows), kh = KV half (1024 keys).
// Per wave: R=32 rows, T=64 keys/iter, 16 iters; merge halves in LDS at end.
// ---------------------------------------------------------------------------
__global__ __launch_bounds__(256, 1)
void flash_kernel(const _Float16* __restrict__ q, const _Float16* __restrict__ FiH,
                  const _Float16* __restrict__ FiT, float* __restrict__ out)
{
    __shared__ __align__(16) _Float16 sP[4][32][72];   // per-wave P [n][m], pad 64->72
    __shared__ __align__(16) float sO[2][32][260];     // kh=1 partial O, pad 256->260
    __shared__ float sM[2][32], sL[2][32];

    const int bid = blockIdx.x;
    const int b  = bid & 7;
    const int nt = bid >> 3;
    const int tid = threadIdx.x;
    const int lane = tid & 63, wave = tid >> 6;
    const int lo = lane & 15, hi = lane >> 4;
    const int rg = wave & 1;        // row group
    const int kh = wave >> 1;       // KV half
    const long nbase = (long)nt * 64 + rg * 32;

    // Q fragments (A layout: A[m=lo][k=hi*8+j]), 2 row-tiles x 8 k-chunks
    half8 qf[2][8];
    const _Float16* qb = q + ((size_t)b * Nn + nbase + lo) * Dd + hi * 8;
#pragma unroll
    for (int rt = 0; rt < 2; ++rt)
#pragma unroll
        for (int kk = 0; kk < 8; ++kk)
            qf[rt][kk] = *reinterpret_cast<const half8*>(qb + rt * 16 * Dd + kk * 32);

    floatx4 o[2][16];
#pragma unroll
    for (int rt = 0; rt < 2; ++rt)
#pragma unroll
        for (int t = 0; t < 16; ++t) o[rt][t] = (floatx4)0.0f;
    float m_i[2][4], l_i[2][4];
#pragma unroll
    for (int rt = 0; rt < 2; ++rt)
#pragma unroll
        for (int r = 0; r < 4; ++r) { m_i[rt][r] = -INFINITY; l_i[rt][r] = 0.f; }

    const _Float16* fH = FiH + (size_t)b * Mm * Dd;
    const _Float16* fT = FiT + (size_t)b * Dd * Mm;

    for (int it = 0; it < 16; ++it) {
        const int key0 = kh * 1024 + it * 64;

        // ---- S = q . Fi^T : 2 row-tiles x 4 key-subtiles, K=256
        floatx4 s[2][4];
#pragma unroll
        for (int rt = 0; rt < 2; ++rt)
#pragma unroll
            for (int st = 0; st < 4; ++st) s[rt][st] = (floatx4)0.0f;
#pragma unroll
        for (int st = 0; st < 4; ++st) {
#pragma unroll
            for (int kk = 0; kk < 8; ++kk) {
                half8 bv = *reinterpret_cast<const half8*>(
                    fH + (size_t)(key0 + st * 16 + lo) * Dd + kk * 32 + hi * 8);
                s[0][st] = MFMA16H(qf[0][kk], bv, s[0][st]);
                s[1][st] = MFMA16H(qf[1][kk], bv, s[1][st]);
            }
        }

        // ---- online softmax (C layout: col=lo=key, row=hi*4+r)
        float alpha[2][4];
#pragma unroll
        for (int rt = 0; rt < 2; ++rt) {
#pragma unroll
            for (int r = 0; r < 4; ++r) {
                float mc = fmaxf(fmaxf(s[rt][0][r], s[rt][1][r]),
                                 fmaxf(s[rt][2][r], s[rt][3][r]));
                mc = fmaxf(mc, __shfl_xor(mc, 1));
                mc = fmaxf(mc, __shfl_xor(mc, 2));
                mc = fmaxf(mc, __shfl_xor(mc, 4));
                mc = fmaxf(mc, __shfl_xor(mc, 8));
                const float mnew = fmaxf(m_i[rt][r], mc);
                alpha[rt][r] = __expf(m_i[rt][r] - mnew);
                float ps = 0.f;
#pragma unroll
                for (int st = 0; st < 4; ++st) {
                    // round p to fp16 FIRST; l sums the ROUNDED values so PV
                    // numerator and denominator use identical weights.
                    _Float16 pb = (_Float16)__expf(s[rt][st][r] - mnew);
                    ps += (float)pb;
                    sP[wave][rt * 16 + hi * 4 + r][st * 16 + lo] = pb;
                }
                ps += __shfl_xor(ps, 1);
                ps += __shfl_xor(ps, 2);
                ps += __shfl_xor(ps, 4);
                ps += __shfl_xor(ps, 8);
                l_i[rt][r] = l_i[rt][r] * alpha[rt][r] + ps;
                m_i[rt][r] = mnew;
            }
        }
#pragma unroll
        for (int rt = 0; rt < 2; ++rt)
#pragma unroll
            for (int t = 0; t < 16; ++t) {
                floatx4 ot = o[rt][t];
#pragma unroll
                for (int r = 0; r < 4; ++r) ot[r] *= alpha[rt][r];
                o[rt][t] = ot;
            }

        // ---- O += P @ Fi : K=64 in 2 chunks; B direct from global FiT
#pragma unroll
        for (int kc = 0; kc < 2; ++kc) {
            half8 pa0 = *reinterpret_cast<const half8*>(&sP[wave][lo][kc * 32 + hi * 8]);
            half8 pa1 = *reinterpret_cast<const half8*>(&sP[wave][16 + lo][kc * 32 + hi * 8]);
#pragma unroll
            for (int t = 0; t < 16; ++t) {
                half8 bv = *reinterpret_cast<const half8*>(
                    fT + (size_t)(t * 16 + lo) * Mm + key0 + kc * 32 + hi * 8);
                o[0][t] = MFMA16H(pa0, bv, o[0][t]);
                o[1][t] = MFMA16H(pa1, bv, o[1][t]);
            }
        }
    }

    // ---- merge KV halves: kh=1 waves publish partials, kh=0 waves combine
    if (kh == 1) {
#pragma unroll
        for (int rt = 0; rt < 2; ++rt) {
#pragma unroll
            for (int t = 0; t < 16; ++t)
#pragma unroll
                for (int r = 0; r < 4; ++r)
                    sO[rg][rt * 16 + hi * 4 + r][t * 16 + lo] = o[rt][t][r];
#pragma unroll
            for (int r = 0; r < 4; ++r) {
                sM[rg][rt * 16 + hi * 4 + r] = m_i[rt][r];
                sL[rg][rt * 16 + hi * 4 + r] = l_i[rt][r];
            }
        }
    }
    __syncthreads();
    if (kh == 0) {
#pragma unroll
        for (int rt = 0; rt < 2; ++rt) {
#pragma unroll
            for (int r = 0; r < 4; ++r) {
                const int row = rt * 16 + hi * 4 + r;
                const float m2 = sM[rg][row], l2 = sL[rg][row];
                const float mm = fmaxf(m_i[rt][r], m2);
                const float f1 = __expf(m_i[rt][r] - mm);
                const float f2 = __expf(m2 - mm);
                const float inv = 1.0f / (l_i[rt][r] * f1 + l2 * f2);
                float* orow = out + ((size_t)b * Nn + nbase + row) * Dd;
#pragma unroll
                for (int t = 0; t < 16; ++t)
                    orow[t * 16 + lo] = (o[rt][t][r] * f1 + sO[rg][row][t * 16 + lo] * f2) * inv;
            }
        }
    }
}

// ---------------------------------------------------------------------------
extern "C" void kernel_launch(void* const* d_in, const int* in_sizes, int n_in,
                              void* d_out, int out_size, void* d_ws, size_t ws_size,
                              hipStream_t stream)
{
    const float* x    = (const float*)d_in[0];
    const float* Fi   = (const float*)d_in[1];
    const float* W    = (const float*)d_in[2];
    const float* bias = (const float*)d_in[3];
    float* out = (float*)d_out;

    _Float16* q_ws = (_Float16*)d_ws;                               // 8.4 MB
    _Float16* FiH  = q_ws + (size_t)Bb * Nn * Dd;                   // 8.4 MB
    _Float16* FiT  = FiH + (size_t)Bb * Mm * Dd;                    // 8.4 MB

    hipLaunchKernelGGL(qproj_kernel, dim3(256), dim3(256), 0, stream, x, W, bias, q_ws);
    hipLaunchKernelGGL(prep_kernel, dim3(1024), dim3(256), 0, stream, Fi, FiH, FiT);
    hipLaunchKernelGGL(flash_kernel, dim3(256), dim3(256), 0, stream, q_ws, FiH, FiT, out);
}